// Round 10
// baseline (211.504 us; speedup 1.0000x reference)
//
#include <hip/hip_runtime.h>
#include <hip/hip_bf16.h>

#define N_NODES 100000
#define N_EDGES 2000000
#define DIM 64
#define NB 391                 // dst-buckets of 256 nodes
#define CAP 8192               // ebuf slots per bucket (mean 5120, sigma ~71)
#define PCAP 8192              // csr slots per bucket (max ~5600 + 256*3 pad < 8192)
#define EPB 4096               // edges per binning block
#define EPT 16                 // EPB / 256
#define BIN_BLOCKS ((N_EDGES + EPB - 1) / EPB)   // 489
#define XCONV_BLOCKS (N_NODES * DIM / 4 / 256)   // 6250 (float4 per thread)
#define LSTRIDE 144            // LDS agg row stride (128 + 16 pad, 16B-aligned)

typedef __attribute__((ext_vector_type(8))) short short8;
typedef __attribute__((ext_vector_type(4))) float f32x4;
typedef __attribute__((ext_vector_type(2))) float f32x2;

// ---------------------------------------------------------------------------
// Combined: blocks [0,BIN_BLOCKS) bin edges into per-bucket runs of ebuf
// (zero-based cursor atomics); next 6250 blocks convert x -> bf16 + fp8;
// last 64 blocks pack W0/W1 into MFMA B-fragments.
__global__ __launch_bounds__(256) void binprep_kernel(const int* __restrict__ src,
                                                      const int* __restrict__ dst,
                                                      int* __restrict__ gbcur,
                                                      int* __restrict__ ebuf,
                                                      const float* __restrict__ x,
                                                      uint2* __restrict__ xb4,
                                                      int* __restrict__ xf8,
                                                      const float* __restrict__ W0,
                                                      const float* __restrict__ W1,
                                                      __hip_bfloat16* __restrict__ wfrag) {
    __shared__ int buf[EPB];        // 16 KB
    __shared__ short bufb[EPB];     // 8 KB
    __shared__ int a[512];
    __shared__ int lscan[NB], lcur[NB], gbase[NB];

    const int bid = blockIdx.x;
    if (bid >= BIN_BLOCKS) {
        const int pb = bid - BIN_BLOCKS;
        if (pb < XCONV_BLOCKS) {                 // x -> bf16x4 + fp8x4
            const int i = pb * 256 + threadIdx.x;
            const float4 v = ((const float4*)x)[i];
            __hip_bfloat162 p0 = __float22bfloat162_rn(make_float2(v.x, v.y));
            __hip_bfloat162 p1 = __float22bfloat162_rn(make_float2(v.z, v.w));
            uint2 ob;
            ob.x = *(unsigned int*)&p0;
            ob.y = *(unsigned int*)&p1;
            xb4[i] = ob;
            int w = __builtin_amdgcn_cvt_pk_fp8_f32(v.x, v.y, 0, false);
            w = __builtin_amdgcn_cvt_pk_fp8_f32(v.z, v.w, w, true);
            xf8[i] = w;
            // first conversion block also zeroes the dummy row N_NODES
            if (pb == 0 && threadIdx.x < 16) xf8[N_NODES * 16 + threadIdx.x] = 0;
        } else {                                  // W fragment pack
            const int tid = (pb - XCONV_BLOCKS) * 256 + threadIdx.x;  // 16384
            const int j    = tid & 7;
            const int lane = (tid >> 3) & 63;
            const int kc   = (tid >> 9) & 3;
            const int nt   = (tid >> 11) & 3;
            const int l    = tid >> 13;
            const int k = kc * 32 + (lane >> 4) * 8 + j;
            const int n = nt * 16 + (lane & 15);
            const float* W = l ? W1 : W0;
            wfrag[tid] = __float2bfloat16(W[k * 64 + n]);
        }
        return;
    }

    // ---- binning block ----
    const int t = threadIdx.x;
    const int e0 = bid * EPB;
    const int cnt = min(EPB, N_EDGES - e0);

    for (int i = t; i < 512; i += 256) a[i] = 0;
    __syncthreads();

    int ls[EPT], ld[EPT];
    #pragma unroll
    for (int k = 0; k < EPT; ++k) {
        const int o = t + k * 256;
        if (o < cnt) {
            ls[k] = src[e0 + o];
            ld[k] = dst[e0 + o];
            atomicAdd(&a[ld[k] >> 8], 1);
        } else ld[k] = -1;
    }
    __syncthreads();

    // Blelloch exclusive scan over a[0..511]
    #pragma unroll
    for (int d = 1; d < 512; d <<= 1) {
        const int idx = (t + 1) * 2 * d - 1;
        if (idx < 512) a[idx] += a[idx - d];
        __syncthreads();
    }
    if (t == 0) a[511] = 0;
    __syncthreads();
    #pragma unroll
    for (int d = 256; d >= 1; d >>= 1) {
        const int idx = (t + 1) * 2 * d - 1;
        if (idx < 512) {
            const int tmp = a[idx - d];
            a[idx - d] = a[idx];
            a[idx] += tmp;
        }
        __syncthreads();
    }
    for (int i = t; i < NB; i += 256) {
        const int c = a[i + 1] - a[i];
        lscan[i] = a[i];
        lcur[i]  = a[i];
        gbase[i] = c ? atomicAdd(&gbcur[i], c) : 0;   // zero-based run base
    }
    __syncthreads();

    #pragma unroll
    for (int k = 0; k < EPT; ++k) {
        if (ld[k] >= 0) {
            const int b = ld[k] >> 8;
            const int p = atomicAdd(&lcur[b], 1);
            buf[p]  = (ls[k] << 8) | (ld[k] & 255);
            bufb[p] = (short)b;
        }
    }
    __syncthreads();
    for (int i = t; i < cnt; i += 256) {
        const int pk = buf[i];
        const int b  = bufb[i];
        ebuf[b * CAP + gbase[b] + (i - lscan[b])] = pk;
    }
}

// ---------------------------------------------------------------------------
// Per-bucket: degree count + scan of 4-padded degrees -> bucket-strided csr
// offsets (nodeinfo = {start, deg}); fill csr; pad each run to x4 with the
// dummy node index N_NODES (zeroed table row). Starts stay 16B-aligned.
__global__ __launch_bounds__(256) void fillpass_kernel(const int* __restrict__ ebuf,
                                                       const int* __restrict__ gbcur,
                                                       int2* __restrict__ nodeinfo,
                                                       int* __restrict__ csr) {
    __shared__ int cnt[256];
    __shared__ int s[256];
    __shared__ int cur[256];
    const int b = blockIdx.x;
    const int t = threadIdx.x;
    const int nbase = b << 8;
    const int ecnt = gbcur[b];
    const int estart = b * CAP;

    cnt[t] = 0;
    __syncthreads();
    for (int i = t; i < ecnt; i += 256)
        atomicAdd(&cnt[ebuf[estart + i] & 255], 1);
    __syncthreads();

    const int deg  = cnt[t];
    const int pdeg = (deg + 3) & ~3;
    s[t] = pdeg;
    __syncthreads();
    #pragma unroll
    for (int off = 1; off < 256; off <<= 1) {   // inclusive scan of padded degs
        int u = (t >= off) ? s[t - off] : 0;
        __syncthreads();
        s[t] += u;
        __syncthreads();
    }
    const int rp = b * PCAP + s[t] - pdeg;      // padded start, bucket-strided
    if (nbase + t < N_NODES) nodeinfo[nbase + t] = make_int2(rp, deg);
    cur[t] = rp;
    __syncthreads();

    for (int i = t; i < ecnt; i += 256) {
        const int pk = ebuf[estart + i];
        const int p = atomicAdd(&cur[pk & 255], 1);
        csr[p] = pk >> 8;
    }
    __syncthreads();
    for (int p = rp + deg; p < rp + pdeg; ++p)  // pad with dummy zero-row index
        csr[p] = N_NODES;
}

// ---------------------------------------------------------------------------
// Fused gather + linear layer. Block = 256 threads handles 64 nodes.
// Phase 1 (gather): 32 groups of 8 lanes; group g gathers nodes base+g and
// base+32+g (lane r privately accumulates dims 8r..8r+7 across neighbors --
// no shuffles). Agg rows parked in LDS (144-B stride).
// Phase 2 (GEMM): 4 waves x 16-row MFMA tiles; A = [hb (global) | agg (LDS)],
// B pre-packed fragments, f32 accumulate, bias+relu fused.
template <bool RELU, bool OUTF32, bool WRF8>
__global__ __launch_bounds__(256) void sage_fused_kernel(
        const uint2* __restrict__ f8tbl,
        const unsigned short* __restrict__ hb,
        const int2* __restrict__ nodeinfo,
        const uint4* __restrict__ csr4,
        const unsigned short* __restrict__ wfrag,
        const float* __restrict__ bias,
        float* __restrict__ outf,
        unsigned short* __restrict__ outb,
        unsigned char* __restrict__ outf8) {
    __shared__ __align__(16) unsigned char aggL[64 * LSTRIDE];  // 9216 B

    const int tid = threadIdx.x;
    const int base = blockIdx.x * 64;

    // ---------------- phase 1: gather 2 nodes per 8-lane group --------------
    {
        const int g = tid >> 3;               // group 0..31
        const int r = tid & 7;                // 8-byte chunk within 64-B row

        #define CONSUME(u, A)                                                 \
            {                                                                 \
                f32x2 f01 = __builtin_amdgcn_cvt_pk_f32_fp8((u).x, false);    \
                f32x2 f23 = __builtin_amdgcn_cvt_pk_f32_fp8((u).x, true);     \
                f32x2 f45 = __builtin_amdgcn_cvt_pk_f32_fp8((u).y, false);    \
                f32x2 f67 = __builtin_amdgcn_cvt_pk_f32_fp8((u).y, true);     \
                A[0] += f01.x; A[1] += f01.y; A[2] += f23.x; A[3] += f23.y;   \
                A[4] += f45.x; A[5] += f45.y; A[6] += f67.x; A[7] += f67.y;   \
            }

        #pragma unroll
        for (int half = 0; half < 2; ++half) {
            const int ln = half * 32 + g;     // local node 0..63
            const int node = base + ln;
            int2 ni = (node < N_NODES) ? nodeinfo[node] : make_int2(0, 0);
            const int c0 = ni.x >> 2;
            const int deg = ni.y;
            const int rounds = (deg + 3) >> 2;

            float acc[8] = {0.f, 0.f, 0.f, 0.f, 0.f, 0.f, 0.f, 0.f};
            for (int t = 0; t < rounds; ++t) {
                const uint4 id = csr4[c0 + t];          // group-uniform
                const uint2 u0 = f8tbl[(size_t)id.x * 8 + r];
                const uint2 u1 = f8tbl[(size_t)id.y * 8 + r];
                const uint2 u2 = f8tbl[(size_t)id.z * 8 + r];
                const uint2 u3 = f8tbl[(size_t)id.w * 8 + r];
                CONSUME(u0, acc); CONSUME(u1, acc); CONSUME(u2, acc); CONSUME(u3, acc);
            }
            const float inv = 1.0f / fmaxf((float)deg, 1.0f);
            __hip_bfloat162 p0 = __float22bfloat162_rn(make_float2(acc[0] * inv, acc[1] * inv));
            __hip_bfloat162 p1 = __float22bfloat162_rn(make_float2(acc[2] * inv, acc[3] * inv));
            __hip_bfloat162 p2 = __float22bfloat162_rn(make_float2(acc[4] * inv, acc[5] * inv));
            __hip_bfloat162 p3 = __float22bfloat162_rn(make_float2(acc[6] * inv, acc[7] * inv));
            uint4 ov;
            ov.x = *(unsigned int*)&p0;
            ov.y = *(unsigned int*)&p1;
            ov.z = *(unsigned int*)&p2;
            ov.w = *(unsigned int*)&p3;
            *(uint4*)(aggL + ln * LSTRIDE + r * 16) = ov;
        }
        #undef CONSUME
    }
    __syncthreads();

    // ---------------- phase 2: MFMA GEMM over the 64 rows -------------------
    {
        const int wave = tid >> 6;
        const int lane = tid & 63;
        const int m0 = base + wave * 16;
        const int quad = lane >> 4;
        const int lrow = lane & 15;
        const int m = min(m0 + lrow, N_NODES - 1);   // clamped (stores guarded)
        const int ln = wave * 16 + lrow;             // local row for agg half

        short8 bf[4][4];
        #pragma unroll
        for (int nt = 0; nt < 4; ++nt)
            #pragma unroll
            for (int kc = 0; kc < 4; ++kc)
                bf[nt][kc] = *(const short8*)(wfrag + (size_t)((nt * 4 + kc) * 64 + lane) * 8);

        f32x4 acc[4];
        #pragma unroll
        for (int nt = 0; nt < 4; ++nt) acc[nt] = f32x4{0.f, 0.f, 0.f, 0.f};

        #pragma unroll
        for (int kc = 0; kc < 4; ++kc) {
            short8 af;
            if (kc < 2) {
                af = *(const short8*)(hb + (size_t)m * 64 + kc * 32 + quad * 8);
            } else {
                af = *(const short8*)(aggL + ln * LSTRIDE + (kc - 2) * 64 + quad * 16);
            }
            #pragma unroll
            for (int nt = 0; nt < 4; ++nt)
                acc[nt] = __builtin_amdgcn_mfma_f32_16x16x32_bf16(af, bf[nt][kc], acc[nt], 0, 0, 0);
        }

        #pragma unroll
        for (int nt = 0; nt < 4; ++nt) {
            const float bv = bias[nt * 16 + lrow];
            #pragma unroll
            for (int r = 0; r < 4; ++r) {
                const int mr = m0 + quad * 4 + r;
                if (mr < N_NODES) {
                    float v = acc[nt][r] + bv;
                    if (RELU) v = fmaxf(v, 0.f);
                    const size_t off = (size_t)mr * 64 + nt * 16 + lrow;
                    if (OUTF32) {
                        outf[off] = v;
                    } else {
                        __hip_bfloat16 hv = __float2bfloat16(v);
                        outb[off] = *(unsigned short*)&hv;
                    }
                    if (WRF8) {
                        const int w8 = __builtin_amdgcn_cvt_pk_fp8_f32(v, v, 0, false);
                        outf8[off] = (unsigned char)(w8 & 0xff);
                    }
                }
            }
        }
        // zero the dummy gather row of the next layer's table
        if (WRF8 && blockIdx.x == 0 && tid < 8)
            ((unsigned long long*)(outf8 + (size_t)N_NODES * DIM))[tid] = 0ULL;
    }
}

// ---------------------------------------------------------------------------
extern "C" void kernel_launch(void* const* d_in, const int* in_sizes, int n_in,
                              void* d_out, int out_size, void* d_ws, size_t ws_size,
                              hipStream_t stream) {
    const float* x  = (const float*)d_in[0];
    const int*   ei = (const int*)d_in[1];
    const float* W0 = (const float*)d_in[2];
    const float* b0 = (const float*)d_in[3];
    const float* W1 = (const float*)d_in[4];
    const float* b1 = (const float*)d_in[5];
    float* out = (float*)d_out;

    const int* src = ei;            // edge_index[0]
    const int* dst = ei + N_EDGES;  // edge_index[1]

    char* ws = (char*)d_ws;
    auto alloc = [&](size_t bytes) {
        char* p = ws;
        ws += (bytes + 255) & ~(size_t)255;
        return p;
    };
    int*  gbcur    = (int*)alloc((size_t)NB * 4);
    int2* nodeinfo = (int2*)alloc((size_t)N_NODES * 8);
    int*  ebuf     = (int*)alloc((size_t)NB * CAP * 4);    // 12.8 MB
    int*  csr      = (int*)alloc((size_t)NB * PCAP * 4);   // 12.8 MB
    unsigned short* xb   = (unsigned short*)alloc((size_t)N_NODES * DIM * 2);
    unsigned char*  xf8  = (unsigned char*)alloc((size_t)(N_NODES + 1) * DIM);
    unsigned short* h1b  = (unsigned short*)alloc((size_t)N_NODES * DIM * 2);
    unsigned char*  h1f8 = (unsigned char*)alloc((size_t)(N_NODES + 1) * DIM);
    __hip_bfloat16* wfrag = (__hip_bfloat16*)alloc((size_t)2 * 8192 * 2);

    hipMemsetAsync(gbcur, 0, (size_t)NB * 4, stream);

    // ---- CSR build + prep (fused): bin -> fill (bucket-strided, 4-padded) --
    binprep_kernel<<<BIN_BLOCKS + XCONV_BLOCKS + 64, 256, 0, stream>>>(
        src, dst, gbcur, ebuf, x, (uint2*)xb, (int*)xf8, W0, W1, wfrag);
    fillpass_kernel<<<NB, 256, 0, stream>>>(ebuf, gbcur, nodeinfo, csr);

    const int fused_blocks = (N_NODES + 63) / 64;   // 1563

    // ---- layer 0: gather(xf8) + GEMM -> h1b (relu, bf16) + h1f8 ----
    sage_fused_kernel<true, false, true><<<fused_blocks, 256, 0, stream>>>(
        (const uint2*)xf8, xb, nodeinfo, (const uint4*)csr,
        (const unsigned short*)wfrag, b0, nullptr, h1b, h1f8);

    // ---- layer 1: gather(h1f8) + GEMM -> out (f32) ----
    sage_fused_kernel<false, true, false><<<fused_blocks, 256, 0, stream>>>(
        (const uint2*)h1f8, h1b, nodeinfo, (const uint4*)csr,
        (const unsigned short*)wfrag + 8192, b1, out, nullptr, nullptr);
}

// Round 11
// 205.012 us; speedup vs baseline: 1.0317x; 1.0317x over previous
//
#include <hip/hip_runtime.h>
#include <hip/hip_bf16.h>

#define N_NODES 100000
#define N_EDGES 2000000
#define DIM 64
#define NB 391                 // dst-buckets of 256 nodes
#define CAP 8192               // ebuf slots per bucket (mean 5120, sigma ~71)
#define PCAP 8192              // csr slots per bucket (max ~5600 + 256*3 pad < 8192)
#define EPB 4096               // edges per binning block
#define EPT 16                 // EPB / 256
#define BIN_BLOCKS ((N_EDGES + EPB - 1) / EPB)   // 489
#define XCONV_BLOCKS (N_NODES * DIM / 4 / 256)   // 6250 (float4 per thread)
#define LSTRIDE 144            // LDS agg row stride (128 + 16 pad, 16B-aligned)

typedef __attribute__((ext_vector_type(8))) short short8;
typedef __attribute__((ext_vector_type(4))) float f32x4;
typedef __attribute__((ext_vector_type(2))) float f32x2;

// ---------------------------------------------------------------------------
// Combined: blocks [0,BIN_BLOCKS) bin edges into per-bucket runs of ebuf
// (zero-based cursor atomics); next 6250 blocks convert x -> bf16 + fp8;
// last 64 blocks pack W0/W1 into MFMA B-fragments.
__global__ __launch_bounds__(256) void binprep_kernel(const int* __restrict__ src,
                                                      const int* __restrict__ dst,
                                                      int* __restrict__ gbcur,
                                                      int* __restrict__ ebuf,
                                                      const float* __restrict__ x,
                                                      uint2* __restrict__ xb4,
                                                      int* __restrict__ xf8,
                                                      const float* __restrict__ W0,
                                                      const float* __restrict__ W1,
                                                      __hip_bfloat16* __restrict__ wfrag) {
    __shared__ int buf[EPB];        // 16 KB
    __shared__ short bufb[EPB];     // 8 KB
    __shared__ int a[512];
    __shared__ int lscan[NB], lcur[NB], gbase[NB];

    const int bid = blockIdx.x;
    if (bid >= BIN_BLOCKS) {
        const int pb = bid - BIN_BLOCKS;
        if (pb < XCONV_BLOCKS) {                 // x -> bf16x4 + fp8x4
            const int i = pb * 256 + threadIdx.x;
            const float4 v = ((const float4*)x)[i];
            __hip_bfloat162 p0 = __float22bfloat162_rn(make_float2(v.x, v.y));
            __hip_bfloat162 p1 = __float22bfloat162_rn(make_float2(v.z, v.w));
            uint2 ob;
            ob.x = *(unsigned int*)&p0;
            ob.y = *(unsigned int*)&p1;
            xb4[i] = ob;
            int w = __builtin_amdgcn_cvt_pk_fp8_f32(v.x, v.y, 0, false);
            w = __builtin_amdgcn_cvt_pk_fp8_f32(v.z, v.w, w, true);
            xf8[i] = w;
            // first conversion block also zeroes the dummy row N_NODES
            if (pb == 0 && threadIdx.x < 16) xf8[N_NODES * 16 + threadIdx.x] = 0;
        } else {                                  // W fragment pack
            const int tid = (pb - XCONV_BLOCKS) * 256 + threadIdx.x;  // 16384
            const int j    = tid & 7;
            const int lane = (tid >> 3) & 63;
            const int kc   = (tid >> 9) & 3;
            const int nt   = (tid >> 11) & 3;
            const int l    = tid >> 13;
            const int k = kc * 32 + (lane >> 4) * 8 + j;
            const int n = nt * 16 + (lane & 15);
            const float* W = l ? W1 : W0;
            wfrag[tid] = __float2bfloat16(W[k * 64 + n]);
        }
        return;
    }

    // ---- binning block ----
    const int t = threadIdx.x;
    const int e0 = bid * EPB;
    const int cnt = min(EPB, N_EDGES - e0);      // always a multiple of 16

    for (int i = t; i < 512; i += 256) a[i] = 0;
    __syncthreads();

    // vectorized edge load: thread t owns edges e0+16t .. e0+16t+15
    int ls[EPT], ld[EPT];
    const bool act = (t * 16) < cnt;
    {
        const int4* s4 = (const int4*)(src + e0 + t * 16);
        const int4* d4 = (const int4*)(dst + e0 + t * 16);
        #pragma unroll
        for (int k = 0; k < 4; ++k) {
            if (act) {
                const int4 sv = s4[k];
                const int4 dv = d4[k];
                ls[4 * k + 0] = sv.x; ld[4 * k + 0] = dv.x;
                ls[4 * k + 1] = sv.y; ld[4 * k + 1] = dv.y;
                ls[4 * k + 2] = sv.z; ld[4 * k + 2] = dv.z;
                ls[4 * k + 3] = sv.w; ld[4 * k + 3] = dv.w;
            } else {
                ld[4 * k + 0] = ld[4 * k + 1] = ld[4 * k + 2] = ld[4 * k + 3] = -1;
            }
        }
    }
    #pragma unroll
    for (int k = 0; k < EPT; ++k)
        if (ld[k] >= 0) atomicAdd(&a[ld[k] >> 8], 1);
    __syncthreads();

    // Blelloch exclusive scan over a[0..511]
    #pragma unroll
    for (int d = 1; d < 512; d <<= 1) {
        const int idx = (t + 1) * 2 * d - 1;
        if (idx < 512) a[idx] += a[idx - d];
        __syncthreads();
    }
    if (t == 0) a[511] = 0;
    __syncthreads();
    #pragma unroll
    for (int d = 256; d >= 1; d >>= 1) {
        const int idx = (t + 1) * 2 * d - 1;
        if (idx < 512) {
            const int tmp = a[idx - d];
            a[idx - d] = a[idx];
            a[idx] += tmp;
        }
        __syncthreads();
    }
    for (int i = t; i < NB; i += 256) {
        const int c = a[i + 1] - a[i];
        lscan[i] = a[i];
        lcur[i]  = a[i];
        gbase[i] = c ? atomicAdd(&gbcur[i], c) : 0;   // zero-based run base
    }
    __syncthreads();

    #pragma unroll
    for (int k = 0; k < EPT; ++k) {
        if (ld[k] >= 0) {
            const int b = ld[k] >> 8;
            const int p = atomicAdd(&lcur[b], 1);
            buf[p]  = (ls[k] << 8) | (ld[k] & 255);
            bufb[p] = (short)b;
        }
    }
    __syncthreads();
    for (int i = t; i < cnt; i += 256) {
        const int pk = buf[i];
        const int b  = bufb[i];
        ebuf[b * CAP + gbase[b] + (i - lscan[b])] = pk;
    }
}

// ---------------------------------------------------------------------------
// Per-bucket: degree count + scan of 4-padded degrees -> bucket-strided csr
// offsets (nodeinfo = {start, deg}); fill csr; pad each run to x4 with the
// dummy node index N_NODES (zeroed table row). Starts stay 16B-aligned.
__global__ __launch_bounds__(256) void fillpass_kernel(const int* __restrict__ ebuf,
                                                       const int* __restrict__ gbcur,
                                                       int2* __restrict__ nodeinfo,
                                                       int* __restrict__ csr) {
    __shared__ int cnt[256];
    __shared__ int s[256];
    __shared__ int cur[256];
    const int b = blockIdx.x;
    const int t = threadIdx.x;
    const int nbase = b << 8;
    const int ecnt = gbcur[b];
    const int estart = b * CAP;

    cnt[t] = 0;
    __syncthreads();
    for (int i = t; i < ecnt; i += 256)
        atomicAdd(&cnt[ebuf[estart + i] & 255], 1);
    __syncthreads();

    const int deg  = cnt[t];
    const int pdeg = (deg + 3) & ~3;
    s[t] = pdeg;
    __syncthreads();
    #pragma unroll
    for (int off = 1; off < 256; off <<= 1) {   // inclusive scan of padded degs
        int u = (t >= off) ? s[t - off] : 0;
        __syncthreads();
        s[t] += u;
        __syncthreads();
    }
    const int rp = b * PCAP + s[t] - pdeg;      // padded start, bucket-strided
    if (nbase + t < N_NODES) nodeinfo[nbase + t] = make_int2(rp, deg);
    cur[t] = rp;
    __syncthreads();

    for (int i = t; i < ecnt; i += 256) {
        const int pk = ebuf[estart + i];
        const int p = atomicAdd(&cur[pk & 255], 1);
        csr[p] = pk >> 8;
    }
    __syncthreads();
    for (int p = rp + deg; p < rp + pdeg; ++p)  // pad with dummy zero-row index
        csr[p] = N_NODES;
}

// ---------------------------------------------------------------------------
// Fused gather + linear layer. Block = 512 threads handles 64 nodes.
// Phase 1 (gather): 64 groups of 8 lanes, ONE node each (balanced like the
// standalone gather); lane r privately accumulates dims 8r..8r+7 across all
// neighbors -- no shuffles. Agg rows parked in LDS (144-B stride).
// Phase 2 (GEMM): 8 waves; wave w = (mtile = w&3, nhalf = w>>2) computes a
// 16-row M-tile x 2 N-tiles. A = [hb (global) | agg (LDS)], B pre-packed
// fragments, f32 accumulate, bias+relu fused.
template <bool RELU, bool OUTF32, bool WRF8>
__global__ __launch_bounds__(512) void sage_fused_kernel(
        const uint2* __restrict__ f8tbl,
        const unsigned short* __restrict__ hb,
        const int2* __restrict__ nodeinfo,
        const uint4* __restrict__ csr4,
        const unsigned short* __restrict__ wfrag,
        const float* __restrict__ bias,
        float* __restrict__ outf,
        unsigned short* __restrict__ outb,
        unsigned char* __restrict__ outf8) {
    __shared__ __align__(16) unsigned char aggL[64 * LSTRIDE];  // 9216 B

    const int tid = threadIdx.x;
    const int base = blockIdx.x * 64;

    // ---------------- phase 1: gather, one node per 8-lane group ------------
    {
        const int g = tid >> 3;               // group / local node 0..63
        const int r = tid & 7;                // 8-byte chunk within 64-B row
        const int node = base + g;
        const int2 ni = (node < N_NODES) ? nodeinfo[node] : make_int2(0, 0);
        const int c0 = ni.x >> 2;
        const int deg = ni.y;
        const int rounds = (deg + 3) >> 2;

        float a0 = 0.f, a1 = 0.f, a2 = 0.f, a3 = 0.f;
        float a4 = 0.f, a5 = 0.f, a6 = 0.f, a7 = 0.f;

        #define CONSUME(u)                                                    \
            {                                                                 \
                f32x2 f01 = __builtin_amdgcn_cvt_pk_f32_fp8((u).x, false);    \
                f32x2 f23 = __builtin_amdgcn_cvt_pk_f32_fp8((u).x, true);     \
                f32x2 f45 = __builtin_amdgcn_cvt_pk_f32_fp8((u).y, false);    \
                f32x2 f67 = __builtin_amdgcn_cvt_pk_f32_fp8((u).y, true);     \
                a0 += f01.x; a1 += f01.y; a2 += f23.x; a3 += f23.y;           \
                a4 += f45.x; a5 += f45.y; a6 += f67.x; a7 += f67.y;           \
            }

        for (int t = 0; t < rounds; ++t) {
            const uint4 id = csr4[c0 + t];            // group-uniform
            const uint2 u0 = f8tbl[(size_t)id.x * 8 + r];
            const uint2 u1 = f8tbl[(size_t)id.y * 8 + r];
            const uint2 u2 = f8tbl[(size_t)id.z * 8 + r];
            const uint2 u3 = f8tbl[(size_t)id.w * 8 + r];
            CONSUME(u0); CONSUME(u1); CONSUME(u2); CONSUME(u3);
        }
        #undef CONSUME

        const float inv = 1.0f / fmaxf((float)deg, 1.0f);
        __hip_bfloat162 p0 = __float22bfloat162_rn(make_float2(a0 * inv, a1 * inv));
        __hip_bfloat162 p1 = __float22bfloat162_rn(make_float2(a2 * inv, a3 * inv));
        __hip_bfloat162 p2 = __float22bfloat162_rn(make_float2(a4 * inv, a5 * inv));
        __hip_bfloat162 p3 = __float22bfloat162_rn(make_float2(a6 * inv, a7 * inv));
        uint4 ov;
        ov.x = *(unsigned int*)&p0;
        ov.y = *(unsigned int*)&p1;
        ov.z = *(unsigned int*)&p2;
        ov.w = *(unsigned int*)&p3;
        *(uint4*)(aggL + g * LSTRIDE + r * 16) = ov;
    }
    __syncthreads();

    // ---------------- phase 2: MFMA GEMM, 8 waves over 64 rows --------------
    {
        const int wave = tid >> 6;
        const int lane = tid & 63;
        const int mtile = wave & 3;
        const int nh = wave >> 2;                    // n-half: nt = nh*2 + {0,1}
        const int m0 = base + mtile * 16;
        const int quad = lane >> 4;
        const int lrow = lane & 15;
        const int m = min(m0 + lrow, N_NODES - 1);   // clamped (stores guarded)
        const int ln = mtile * 16 + lrow;            // local row for agg half

        short8 bf[2][4];
        #pragma unroll
        for (int n2 = 0; n2 < 2; ++n2) {
            const int nt = nh * 2 + n2;
            #pragma unroll
            for (int kc = 0; kc < 4; ++kc)
                bf[n2][kc] = *(const short8*)(wfrag + (size_t)((nt * 4 + kc) * 64 + lane) * 8);
        }

        f32x4 acc[2];
        #pragma unroll
        for (int n2 = 0; n2 < 2; ++n2) acc[n2] = f32x4{0.f, 0.f, 0.f, 0.f};

        #pragma unroll
        for (int kc = 0; kc < 4; ++kc) {
            short8 af;
            if (kc < 2) {
                af = *(const short8*)(hb + (size_t)m * 64 + kc * 32 + quad * 8);
            } else {
                af = *(const short8*)(aggL + ln * LSTRIDE + (kc - 2) * 64 + quad * 16);
            }
            #pragma unroll
            for (int n2 = 0; n2 < 2; ++n2)
                acc[n2] = __builtin_amdgcn_mfma_f32_16x16x32_bf16(af, bf[n2][kc], acc[n2], 0, 0, 0);
        }

        #pragma unroll
        for (int n2 = 0; n2 < 2; ++n2) {
            const int nt = nh * 2 + n2;
            const float bv = bias[nt * 16 + lrow];
            #pragma unroll
            for (int r = 0; r < 4; ++r) {
                const int mr = m0 + quad * 4 + r;
                if (mr < N_NODES) {
                    float v = acc[n2][r] + bv;
                    if (RELU) v = fmaxf(v, 0.f);
                    const size_t off = (size_t)mr * 64 + nt * 16 + lrow;
                    if (OUTF32) {
                        outf[off] = v;
                    } else {
                        __hip_bfloat16 hv = __float2bfloat16(v);
                        outb[off] = *(unsigned short*)&hv;
                    }
                    if (WRF8) {
                        const int w8 = __builtin_amdgcn_cvt_pk_fp8_f32(v, v, 0, false);
                        outf8[off] = (unsigned char)(w8 & 0xff);
                    }
                }
            }
        }
        // zero the dummy gather row of the next layer's table
        if (WRF8 && blockIdx.x == 0 && tid < 8)
            ((unsigned long long*)(outf8 + (size_t)N_NODES * DIM))[tid] = 0ULL;
    }
}

// ---------------------------------------------------------------------------
extern "C" void kernel_launch(void* const* d_in, const int* in_sizes, int n_in,
                              void* d_out, int out_size, void* d_ws, size_t ws_size,
                              hipStream_t stream) {
    const float* x  = (const float*)d_in[0];
    const int*   ei = (const int*)d_in[1];
    const float* W0 = (const float*)d_in[2];
    const float* b0 = (const float*)d_in[3];
    const float* W1 = (const float*)d_in[4];
    const float* b1 = (const float*)d_in[5];
    float* out = (float*)d_out;

    const int* src = ei;            // edge_index[0]
    const int* dst = ei + N_EDGES;  // edge_index[1]

    char* ws = (char*)d_ws;
    auto alloc = [&](size_t bytes) {
        char* p = ws;
        ws += (bytes + 255) & ~(size_t)255;
        return p;
    };
    int*  gbcur    = (int*)alloc((size_t)NB * 4);
    int2* nodeinfo = (int2*)alloc((size_t)N_NODES * 8);
    int*  ebuf     = (int*)alloc((size_t)NB * CAP * 4);    // 12.8 MB
    int*  csr      = (int*)alloc((size_t)NB * PCAP * 4);   // 12.8 MB
    unsigned short* xb   = (unsigned short*)alloc((size_t)N_NODES * DIM * 2);
    unsigned char*  xf8  = (unsigned char*)alloc((size_t)(N_NODES + 1) * DIM);
    unsigned short* h1b  = (unsigned short*)alloc((size_t)N_NODES * DIM * 2);
    unsigned char*  h1f8 = (unsigned char*)alloc((size_t)(N_NODES + 1) * DIM);
    __hip_bfloat16* wfrag = (__hip_bfloat16*)alloc((size_t)2 * 8192 * 2);

    hipMemsetAsync(gbcur, 0, (size_t)NB * 4, stream);

    // ---- CSR build + prep (fused): bin -> fill (bucket-strided, 4-padded) --
    binprep_kernel<<<BIN_BLOCKS + XCONV_BLOCKS + 64, 256, 0, stream>>>(
        src, dst, gbcur, ebuf, x, (uint2*)xb, (int*)xf8, W0, W1, wfrag);
    fillpass_kernel<<<NB, 256, 0, stream>>>(ebuf, gbcur, nodeinfo, csr);

    const int fused_blocks = (N_NODES + 63) / 64;   // 1563

    // ---- layer 0: gather(xf8) + GEMM -> h1b (relu, bf16) + h1f8 ----
    sage_fused_kernel<true, false, true><<<fused_blocks, 512, 0, stream>>>(
        (const uint2*)xf8, xb, nodeinfo, (const uint4*)csr,
        (const unsigned short*)wfrag, b0, nullptr, h1b, h1f8);

    // ---- layer 1: gather(h1f8) + GEMM -> out (f32) ----
    sage_fused_kernel<false, true, false><<<fused_blocks, 512, 0, stream>>>(
        (const uint2*)h1f8, h1b, nodeinfo, (const uint4*)csr,
        (const unsigned short*)wfrag + 8192, b1, out, nullptr, nullptr);
}